// Round 5
// baseline (688.962 us; speedup 1.0000x reference)
//
#include <hip/hip_runtime.h>
#include <hip/hip_bf16.h>

// Performer fast-attention, bf16-MFMA pipeline (fused prep/rowsum/dd):
//  1. zero:      k1 (512) + dd (65536) fp32 accumulators
//  2. prep_omega: omega fp32 -> bf16
//  3. phiK fused: reads K fp32 (reg-stage cast + in-stage norms),
//                 writes K_hat^T bf16 [512][65536], atomic k1 += col sums
//  4. prep_VT:    V fp32 -> V^T bf16 [512][n]
//  5. kv GEMM:    split-K (32) NT GEMM -> fp32 partials (aliased into d_out)
//  6. phiQ fused: reads Q fp32, writes Q_hat bf16 [65536][512],
//                 atomic dd += (exp-row) . k1
//  7. reduce_kv:  partials -> kvT bf16 [512][512]
//  8. final GEMM: out = (Q_hat @ kv) / dd

typedef __bf16 bf16x8 __attribute__((ext_vector_type(8)));
typedef float f32x4 __attribute__((ext_vector_type(4)));
typedef unsigned short ushort_t;
typedef ushort_t u16x8 __attribute__((ext_vector_type(8)));
typedef ushort_t u16x4 __attribute__((ext_vector_type(4)));

#define N_NODES 65536
#define FEAT 512

__device__ __forceinline__ ushort_t f2b(float f) {
  unsigned u = __builtin_bit_cast(unsigned, f);
  unsigned r = (u + 0x7fffu + ((u >> 16) & 1u)) >> 16;
  return (ushort_t)r;
}
__device__ __forceinline__ float b2f(ushort_t u) {
  return __builtin_bit_cast(float, ((unsigned)u) << 16);
}

__device__ __forceinline__ void load16(const ushort_t* g, ushort_t* l) {
  __builtin_amdgcn_global_load_lds((const __attribute__((address_space(1))) void*)g,
                                   (__attribute__((address_space(3))) void*)l, 16, 0, 0);
}

__global__ __launch_bounds__(256) void k_zero(float* __restrict__ p, int n) {
  int i = blockIdx.x * 256 + threadIdx.x;
  if (i < n) p[i] = 0.f;
}

// ---- shared 128x128-tile NT GEMM core (BK=64, 4 waves, each 64x64) ----
__device__ __forceinline__ void gemm_tile(const ushort_t* A, const ushort_t* B,
                                          long lda, long ldb, int ksteps,
                                          ushort_t* lA, ushort_t* lB, f32x4 acc[4][4]) {
  const int tid = threadIdx.x;
  const int lane = tid & 63;
  const int wid = tid >> 6;
  const int wr = wid >> 1, wc = wid & 1;
  const int lrow = lane & 15;
  const int lk8 = (lane >> 4) * 8;

  for (int kt = 0; kt < ksteps; ++kt) {
    const ushort_t* Ak = A + (size_t)kt * 64;
    const ushort_t* Bk = B + (size_t)kt * 64;
#pragma unroll
    for (int r = 0; r < 4; ++r) {
      int slot = tid + r * 256;          // 0..1023, 16B each
      int row = slot >> 3;
      int col = (slot & 7) * 8;
      load16(Ak + (size_t)row * lda + col, lA + slot * 8);
      load16(Bk + (size_t)row * ldb + col, lB + slot * 8);
    }
    __syncthreads();
#pragma unroll
    for (int ks = 0; ks < 2; ++ks) {
      bf16x8 af[4], bb[4];
#pragma unroll
      for (int mi = 0; mi < 4; ++mi)
        af[mi] = *(const bf16x8*)(lA + ((wr * 64 + mi * 16 + lrow) * 64 + ks * 32 + lk8));
#pragma unroll
      for (int ni = 0; ni < 4; ++ni)
        bb[ni] = *(const bf16x8*)(lB + ((wc * 64 + ni * 16 + lrow) * 64 + ks * 32 + lk8));
#pragma unroll
      for (int mi = 0; mi < 4; ++mi)
#pragma unroll
        for (int ni = 0; ni < 4; ++ni)
          acc[mi][ni] = __builtin_amdgcn_mfma_f32_16x16x32_bf16(af[mi], bb[ni], acc[mi][ni], 0, 0, 0);
    }
    __syncthreads();
  }
}

__global__ __launch_bounds__(256) void k_prep_omega(const float* __restrict__ om,
                                                    ushort_t* __restrict__ Ob) {
  int i = blockIdx.x * 256 + threadIdx.x;   // 65536 float4 slots
  float4 v = ((const float4*)om)[i];
  u16x4 o = {f2b(v.x), f2b(v.y), f2b(v.z), f2b(v.w)};
  ((u16x4*)Ob)[i] = o;
}

// ---- V fp32 [n][512] -> VT bf16 [512][n] ----
__global__ __launch_bounds__(256) void k_vt(const float* __restrict__ V,
                                            ushort_t* __restrict__ VT) {
  __shared__ ushort_t t[64][72];
  int r0 = blockIdx.x * 64;   // node base
  int c0 = blockIdx.y * 64;   // feature(d) base
#pragma unroll
  for (int it = 0; it < 4; ++it) {
    int slot = threadIdx.x + it * 256;  // 0..1023
    int r = slot >> 4;
    int c4 = slot & 15;
    float4 v = *(const float4*)(V + (size_t)(r0 + r) * FEAT + c0 + c4 * 4);
    u16x4 p = {f2b(v.x), f2b(v.y), f2b(v.z), f2b(v.w)};
    *(u16x4*)&t[r][c4 * 4] = p;
  }
  __syncthreads();
#pragma unroll
  for (int it = 0; it < 2; ++it) {
    int slot = threadIdx.x + it * 256;  // 0..511
    int dr = slot >> 3;
    int n8 = slot & 7;
    u16x8 o;
#pragma unroll
    for (int j = 0; j < 8; ++j) o[j] = t[n8 * 8 + j][dr];
    *(u16x8*)(VT + (size_t)(c0 + dr) * N_NODES + r0 + n8 * 8) = o;
  }
}

// ---- fused phi GEMM: C = exp(X @ omega^T - ||x||^2/2 - ln(sqrt(512)))
//  TRANSK=1: store C^T column-major, atomicAdd column sums into k1w
//  TRANSK=0: store C row-major, atomicAdd (C-row . k1) into dd
template <int TRANSK>
__global__ __launch_bounds__(256) void k_phi_fused(const float* __restrict__ X,
                                                   const ushort_t* __restrict__ Ob,
                                                   const float* __restrict__ k1,
                                                   float* __restrict__ k1w,
                                                   float* __restrict__ dd,
                                                   ushort_t* __restrict__ Out) {
  __shared__ ushort_t lA[128 * 64], lB[128 * 64];
  __shared__ float cvbuf[128];
  f32x4 acc[4][4];
#pragma unroll
  for (int i = 0; i < 4; ++i)
#pragma unroll
    for (int j = 0; j < 4; ++j) acc[i][j] = (f32x4){0.f, 0.f, 0.f, 0.f};

  const int tid = threadIdx.x;
  const int lane = tid & 63;
  const int wid = tid >> 6;
  const int wr = wid >> 1, wc = wid & 1;
  const int lrow = lane & 15;
  const int lk8 = (lane >> 4) * 8;
  const int m0 = blockIdx.y * 128, n0 = blockIdx.x * 128;
  const float* Ax = X + (size_t)m0 * FEAT;
  const ushort_t* Bo = Ob + (size_t)n0 * FEAT;
  const int arow = tid >> 3;        // 0..31
  const int acol = (tid & 7) * 8;
  float nacc[4] = {0.f, 0.f, 0.f, 0.f};

  for (int kt = 0; kt < 8; ++kt) {
    // B staging via global_load_lds (bf16, pre-converted omega)
#pragma unroll
    for (int r = 0; r < 4; ++r) {
      int slot = tid + r * 256;
      int row = slot >> 3;
      int col = (slot & 7) * 8;
      load16(Bo + (size_t)row * FEAT + kt * 64 + col, lB + slot * 8);
    }
    // A reg-staging: fp32 load -> norm accum -> bf16 -> LDS
#pragma unroll
    for (int r = 0; r < 4; ++r) {
      int row = arow + r * 32;
      const float* src = Ax + (size_t)row * FEAT + kt * 64 + acol;
      float4 a0 = *(const float4*)src;
      float4 a1 = *(const float4*)(src + 4);
      nacc[r] += a0.x * a0.x + a0.y * a0.y + a0.z * a0.z + a0.w * a0.w
               + a1.x * a1.x + a1.y * a1.y + a1.z * a1.z + a1.w * a1.w;
      u16x8 p = {f2b(a0.x), f2b(a0.y), f2b(a0.z), f2b(a0.w),
                 f2b(a1.x), f2b(a1.y), f2b(a1.z), f2b(a1.w)};
      *(u16x8*)(lA + (size_t)(tid + r * 256) * 8) = p;
    }
    __syncthreads();
#pragma unroll
    for (int ks = 0; ks < 2; ++ks) {
      bf16x8 af[4], bb[4];
#pragma unroll
      for (int mi = 0; mi < 4; ++mi)
        af[mi] = *(const bf16x8*)(lA + ((wr * 64 + mi * 16 + lrow) * 64 + ks * 32 + lk8));
#pragma unroll
      for (int ni = 0; ni < 4; ++ni)
        bb[ni] = *(const bf16x8*)(lB + ((wc * 64 + ni * 16 + lrow) * 64 + ks * 32 + lk8));
#pragma unroll
      for (int mi = 0; mi < 4; ++mi)
#pragma unroll
        for (int ni = 0; ni < 4; ++ni)
          acc[mi][ni] = __builtin_amdgcn_mfma_f32_16x16x32_bf16(af[mi], bb[ni], acc[mi][ni], 0, 0, 0);
    }
    __syncthreads();
  }

  // norm reduce (8 threads share a row) -> cvbuf[local row]
#pragma unroll
  for (int r = 0; r < 4; ++r) {
    float s = nacc[r];
    s += __shfl_xor(s, 1, 64);
    s += __shfl_xor(s, 2, 64);
    s += __shfl_xor(s, 4, 64);
    if ((lane & 7) == 0) cvbuf[arow + r * 32] = -0.5f * s - 3.11916231f;  // -0.5*ln(512)
  }
  __syncthreads();

  // epilogue
  const int cbase = n0 + wc * 64 + lrow;
  const int lrbase = wr * 64 + ((lane >> 4) << 2);
  float colp[4] = {0.f, 0.f, 0.f, 0.f};
  float k1v[4];
  if (!TRANSK) {
#pragma unroll
    for (int ni = 0; ni < 4; ++ni) k1v[ni] = k1[cbase + ni * 16];
  }
#pragma unroll
  for (int mi = 0; mi < 4; ++mi) {
    int lr0 = lrbase + mi * 16;
    float cv[4];
#pragma unroll
    for (int j = 0; j < 4; ++j) cv[j] = cvbuf[lr0 + j];
    if (TRANSK) {
#pragma unroll
      for (int ni = 0; ni < 4; ++ni) {
        int col = cbase + ni * 16;
        u16x4 pk;
#pragma unroll
        for (int j = 0; j < 4; ++j) {
          float e = __expf(acc[mi][ni][j] + cv[j]);
          pk[j] = f2b(e);
          colp[ni] += e;
        }
        *(u16x4*)(Out + (size_t)col * N_NODES + m0 + lr0) = pk;
      }
    } else {
#pragma unroll
      for (int j = 0; j < 4; ++j) {
        float t = 0.f;
#pragma unroll
        for (int ni = 0; ni < 4; ++ni) {
          float e = __expf(acc[mi][ni][j] + cv[j]);
          Out[(size_t)(m0 + lr0 + j) * FEAT + cbase + ni * 16] = f2b(e);
          t += e * k1v[ni];
        }
        t += __shfl_xor(t, 1, 64);
        t += __shfl_xor(t, 2, 64);
        t += __shfl_xor(t, 4, 64);
        t += __shfl_xor(t, 8, 64);
        if (lrow == 0) atomicAdd(&dd[m0 + lr0 + j], t);
      }
    }
  }
  if (TRANSK) {
#pragma unroll
    for (int ni = 0; ni < 4; ++ni) {
      float t = colp[ni];
      t += __shfl_xor(t, 16, 64);
      t += __shfl_xor(t, 32, 64);
      if (lane < 16) atomicAdd(&k1w[n0 + wc * 64 + lane + ni * 16], t);
    }
  }
}

// ---- kv split-K GEMM: partials[z][feat][d] ----
__global__ __launch_bounds__(256) void k_kv(const ushort_t* __restrict__ KT,
                                            const ushort_t* __restrict__ VT,
                                            float* __restrict__ P) {
  __shared__ ushort_t lA[128 * 64], lB[128 * 64];
  f32x4 acc[4][4];
#pragma unroll
  for (int i = 0; i < 4; ++i)
#pragma unroll
    for (int j = 0; j < 4; ++j) acc[i][j] = (f32x4){0.f, 0.f, 0.f, 0.f};
  const int m0 = blockIdx.y * 128, n0 = blockIdx.x * 128, z = blockIdx.z;
  gemm_tile(KT + (size_t)m0 * N_NODES + z * 2048,
            VT + (size_t)n0 * N_NODES + z * 2048, N_NODES, N_NODES, 32, lA, lB, acc);
  float* Pz = P + (size_t)z * (FEAT * FEAT);
  const int lane = threadIdx.x & 63, wid = threadIdx.x >> 6;
  const int wr = wid >> 1, wc = wid & 1;
  const int cbase = n0 + wc * 64 + (lane & 15);
  const int rbase = m0 + wr * 64 + ((lane >> 4) << 2);
#pragma unroll
  for (int mi = 0; mi < 4; ++mi)
#pragma unroll
    for (int ni = 0; ni < 4; ++ni)
#pragma unroll
      for (int j = 0; j < 4; ++j)
        Pz[(size_t)(rbase + mi * 16 + j) * FEAT + cbase + ni * 16] = acc[mi][ni][j];
}

// ---- reduce partials -> kvT bf16 [d][feat] ----
__global__ __launch_bounds__(256) void k_redkv(const float* __restrict__ P,
                                               ushort_t* __restrict__ kvT) {
  int t = blockIdx.x * 256 + threadIdx.x;  // 0..65535
  int m = t >> 7;       // feat 0..511
  int d4 = t & 127;     // d/4
  float4 s = {0.f, 0.f, 0.f, 0.f};
  for (int z = 0; z < 32; ++z) {
    float4 v = *(const float4*)(P + (size_t)z * (FEAT * FEAT) + (size_t)m * FEAT + d4 * 4);
    s.x += v.x; s.y += v.y; s.z += v.z; s.w += v.w;
  }
  kvT[(size_t)(d4 * 4 + 0) * FEAT + m] = f2b(s.x);
  kvT[(size_t)(d4 * 4 + 1) * FEAT + m] = f2b(s.y);
  kvT[(size_t)(d4 * 4 + 2) * FEAT + m] = f2b(s.z);
  kvT[(size_t)(d4 * 4 + 3) * FEAT + m] = f2b(s.w);
}

// ---- final GEMM: out = (Q_hat @ kv) / dd ----
__global__ __launch_bounds__(256) void k_final(const ushort_t* __restrict__ Qh,
                                               const ushort_t* __restrict__ kvT,
                                               const float* __restrict__ dd,
                                               float* __restrict__ out) {
  __shared__ ushort_t lA[128 * 64], lB[128 * 64];
  f32x4 acc[4][4];
#pragma unroll
  for (int i = 0; i < 4; ++i)
#pragma unroll
    for (int j = 0; j < 4; ++j) acc[i][j] = (f32x4){0.f, 0.f, 0.f, 0.f};
  const int m0 = blockIdx.y * 128, n0 = blockIdx.x * 128;
  gemm_tile(Qh + (size_t)m0 * FEAT, kvT + (size_t)n0 * FEAT, FEAT, FEAT, 8, lA, lB, acc);
  const int lane = threadIdx.x & 63, wid = threadIdx.x >> 6;
  const int wr = wid >> 1, wc = wid & 1;
  const int cbase = n0 + wc * 64 + (lane & 15);
  const int rbase = m0 + wr * 64 + ((lane >> 4) << 2);
#pragma unroll
  for (int mi = 0; mi < 4; ++mi) {
    int r0 = rbase + mi * 16;
    float inv[4];
#pragma unroll
    for (int j = 0; j < 4; ++j) inv[j] = 1.0f / dd[r0 + j];
#pragma unroll
    for (int ni = 0; ni < 4; ++ni) {
      int col = cbase + ni * 16;
#pragma unroll
      for (int j = 0; j < 4; ++j)
        out[(size_t)(r0 + j) * FEAT + col] = acc[mi][ni][j] * inv[j];
    }
  }
}

extern "C" void kernel_launch(void* const* d_in, const int* in_sizes, int n_in,
                              void* d_out, int out_size, void* d_ws, size_t ws_size,
                              hipStream_t stream) {
  const float* Q = (const float*)d_in[0];
  const float* K = (const float*)d_in[1];
  const float* V = (const float*)d_in[2];
  const float* omega = (const float*)d_in[3];
  float* out = (float*)d_out;

  char* ws = (char*)d_ws;
  ushort_t* B1  = (ushort_t*)(ws);                  // 64 MB: V^T
  ushort_t* B2  = (ushort_t*)(ws + 67108864);       // 64 MB: K_hat^T -> Q_hat
  ushort_t* Ob  = (ushort_t*)(ws + 134217728);      // 512 KB omega bf16
  ushort_t* kvT = (ushort_t*)(ws + 134742016);      // 512 KB kv^T bf16
  float*    k1  = (float*)(ws + 135266304);         // 2 KB k_ones
  float*    dd  = (float*)(ws + 135268352);         // 256 KB d_diag (contiguous after k1)
  // split-K partials (32 MB) aliased into d_out: fully consumed by k_redkv
  // before k_final overwrites d_out (stream-ordered).
  float*    P   = (float*)d_out;

  k_zero<<<(512 + 65536 + 255) / 256, 256, 0, stream>>>(k1, 512 + 65536);
  k_prep_omega<<<256, 256, 0, stream>>>(omega, Ob);
  k_phi_fused<1><<<dim3(4, 512), 256, 0, stream>>>(K, Ob, k1, k1, dd, B2);  // -> K_hat^T, k1
  k_vt<<<dim3(N_NODES / 64, 8), 256, 0, stream>>>(V, B1);                   // -> V^T
  k_kv<<<dim3(4, 4, 32), 256, 0, stream>>>(B2, B1, P);
  k_phi_fused<0><<<dim3(4, 512), 256, 0, stream>>>(Q, Ob, k1, k1, dd, B2);  // -> Q_hat, dd
  k_redkv<<<256, 256, 0, stream>>>(P, kvT);
  k_final<<<dim3(4, 512), 256, 0, stream>>>(B2, kvT, dd, out);
}

// Round 8
// 665.890 us; speedup vs baseline: 1.0346x; 1.0346x over previous
//
#include <hip/hip_runtime.h>
#include <hip/hip_bf16.h>

// Performer fast-attention, bf16-MFMA pipeline.
// T2 XOR-granule LDS swizzle (src-preswizzled, global layouts unchanged)
// in all GEMM staging + ds_reads; A-reg prefetch in phi (T14); merged init.
// 7 dispatches:
//  1. init:      omega fp32->bf16, zero k1+dd
//  2. phiK fused: K fp32 -> K_hat^T bf16 [512][65536], atomic k1 += col sums
//  3. prep_VT:   V fp32 -> V^T bf16 [512][n]
//  4. kv GEMM:   split-K (32) NT GEMM -> fp32 partials (aliased into d_out)
//  5. phiQ fused: Q fp32 -> Q_hat bf16 [65536][512], atomic dd += row . k1
//  6. reduce_kv: partials -> kvT bf16 [512][512]
//  7. final GEMM: out = (Q_hat @ kv) / dd

typedef __bf16 bf16x8 __attribute__((ext_vector_type(8)));
typedef float f32x4 __attribute__((ext_vector_type(4)));
typedef unsigned short ushort_t;
typedef ushort_t u16x8 __attribute__((ext_vector_type(8)));
typedef ushort_t u16x4 __attribute__((ext_vector_type(4)));

#define N_NODES 65536
#define FEAT 512

__device__ __forceinline__ ushort_t f2b(float f) {
  unsigned u = __builtin_bit_cast(unsigned, f);
  unsigned r = (u + 0x7fffu + ((u >> 16) & 1u)) >> 16;
  return (ushort_t)r;
}
__device__ __forceinline__ float b2f(ushort_t u) {
  return __builtin_bit_cast(float, ((unsigned)u) << 16);
}

__device__ __forceinline__ void load16(const ushort_t* g, ushort_t* l) {
  __builtin_amdgcn_global_load_lds((const __attribute__((address_space(1))) void*)g,
                                   (__attribute__((address_space(3))) void*)l, 16, 0, 0);
}

// LDS tile layout: [128 rows][64 cols] bf16, 8 granules of 16B per row.
// Swizzle: LDS granule gl of row r holds GLOBAL granule gl ^ (r&7).
// ds_read of logical granule g reads LDS granule g ^ (r&7) -> 2-way max.

// ---- merged init: omega fp32 -> bf16 (blocks 0..255), zero k1+dd (blocks 256..) ----
__global__ __launch_bounds__(256) void k_init(const float* __restrict__ om,
                                              ushort_t* __restrict__ Ob,
                                              float* __restrict__ zp, int zn) {
  int b = blockIdx.x;
  if (b < 256) {
    int i = b * 256 + threadIdx.x;
    float4 v = ((const float4*)om)[i];
    u16x4 o = {f2b(v.x), f2b(v.y), f2b(v.z), f2b(v.w)};
    ((u16x4*)Ob)[i] = o;
  } else {
    int i = (b - 256) * 256 + threadIdx.x;
    if (i < zn) zp[i] = 0.f;
  }
}

// ---- shared 128x128-tile NT GEMM core (BK=64, 4 waves, swizzled LDS) ----
__device__ __forceinline__ void gemm_tile(const ushort_t* A, const ushort_t* B,
                                          long lda, long ldb, int ksteps,
                                          ushort_t* lA, ushort_t* lB, f32x4 acc[4][4]) {
  const int tid = threadIdx.x;
  const int lane = tid & 63;
  const int wid = tid >> 6;
  const int wr = wid >> 1, wc = wid & 1;
  const int lrow = lane & 15;
  const int swz = lrow & 7;

  for (int kt = 0; kt < ksteps; ++kt) {
    const ushort_t* Ak = A + (size_t)kt * 64;
    const ushort_t* Bk = B + (size_t)kt * 64;
#pragma unroll
    for (int r = 0; r < 4; ++r) {
      int slot = tid + r * 256;          // 0..1023, 16B each, linear LDS dest
      int row = slot >> 3;
      int gsrc = (slot & 7) ^ (row & 7); // pre-swizzled global source granule
      load16(Ak + (size_t)row * lda + gsrc * 8, lA + slot * 8);
      load16(Bk + (size_t)row * ldb + gsrc * 8, lB + slot * 8);
    }
    __syncthreads();
#pragma unroll
    for (int ks = 0; ks < 2; ++ks) {
      const int gsw = ((ks * 4 + (lane >> 4)) ^ swz) * 8;  // swizzled granule offset
      bf16x8 af[4], bb[4];
#pragma unroll
      for (int mi = 0; mi < 4; ++mi)
        af[mi] = *(const bf16x8*)(lA + ((wr * 64 + mi * 16 + lrow) * 64 + gsw));
#pragma unroll
      for (int ni = 0; ni < 4; ++ni)
        bb[ni] = *(const bf16x8*)(lB + ((wc * 64 + ni * 16 + lrow) * 64 + gsw));
#pragma unroll
      for (int mi = 0; mi < 4; ++mi)
#pragma unroll
        for (int ni = 0; ni < 4; ++ni)
          acc[mi][ni] = __builtin_amdgcn_mfma_f32_16x16x32_bf16(af[mi], bb[ni], acc[mi][ni], 0, 0, 0);
    }
    __syncthreads();
  }
}

// ---- V fp32 [n][512] -> VT bf16 [512][n] ----
__global__ __launch_bounds__(256) void k_vt(const float* __restrict__ V,
                                            ushort_t* __restrict__ VT) {
  __shared__ ushort_t t[64][72];
  int r0 = blockIdx.x * 64;   // node base
  int c0 = blockIdx.y * 64;   // feature(d) base
#pragma unroll
  for (int it = 0; it < 4; ++it) {
    int slot = threadIdx.x + it * 256;  // 0..1023
    int r = slot >> 4;
    int c4 = slot & 15;
    float4 v = *(const float4*)(V + (size_t)(r0 + r) * FEAT + c0 + c4 * 4);
    u16x4 p = {f2b(v.x), f2b(v.y), f2b(v.z), f2b(v.w)};
    *(u16x4*)&t[r][c4 * 4] = p;
  }
  __syncthreads();
#pragma unroll
  for (int it = 0; it < 2; ++it) {
    int slot = threadIdx.x + it * 256;  // 0..511
    int dr = slot >> 3;
    int n8 = slot & 7;
    u16x8 o;
#pragma unroll
    for (int j = 0; j < 8; ++j) o[j] = t[n8 * 8 + j][dr];
    *(u16x8*)(VT + (size_t)(c0 + dr) * N_NODES + r0 + n8 * 8) = o;
  }
}

// ---- fused phi GEMM: C = exp(X @ omega^T - ||x||^2/2 - ln(sqrt(512)))
//  TRANSK=1: store C^T column-major, atomicAdd column sums into k1w
//  TRANSK=0: store C row-major, atomicAdd (C-row . k1) into dd
template <int TRANSK>
__global__ __launch_bounds__(256) void k_phi_fused(const float* __restrict__ X,
                                                   const ushort_t* __restrict__ Ob,
                                                   const float* __restrict__ k1,
                                                   float* __restrict__ k1w,
                                                   float* __restrict__ dd,
                                                   ushort_t* __restrict__ Out) {
  __shared__ ushort_t lA[128 * 64], lB[128 * 64];
  __shared__ float cvbuf[128];
  f32x4 acc[4][4];
#pragma unroll
  for (int i = 0; i < 4; ++i)
#pragma unroll
    for (int j = 0; j < 4; ++j) acc[i][j] = (f32x4){0.f, 0.f, 0.f, 0.f};

  const int tid = threadIdx.x;
  const int lane = tid & 63;
  const int wid = tid >> 6;
  const int wr = wid >> 1, wc = wid & 1;
  const int lrow = lane & 15;
  const int swz = lrow & 7;
  const int m0 = blockIdx.y * 128, n0 = blockIdx.x * 128;
  const float* Ax = X + (size_t)m0 * FEAT;
  const ushort_t* Bo = Ob + (size_t)n0 * FEAT;
  const int arow = tid >> 3;        // 0..31 (local row of this thread's A chunk)
  const int acol = (tid & 7) * 8;   // global granule (8 fp32) within the K-step
  float nacc[4] = {0.f, 0.f, 0.f, 0.f};

  // A(kt=0) prefetch into regs
  float4 pa0[4], pa1[4];
#pragma unroll
  for (int r = 0; r < 4; ++r) {
    const float* src = Ax + (size_t)(arow + r * 32) * FEAT + acol;
    pa0[r] = *(const float4*)src;
    pa1[r] = *(const float4*)(src + 4);
  }

  for (int kt = 0; kt < 8; ++kt) {
    // B staging via global_load_lds, pre-swizzled source
#pragma unroll
    for (int r = 0; r < 4; ++r) {
      int slot = tid + r * 256;
      int row = slot >> 3;
      int gsrc = (slot & 7) ^ (row & 7);
      load16(Bo + (size_t)row * FEAT + kt * 64 + gsrc * 8, lB + slot * 8);
    }
    // A: consume prefetched regs -> norm accum -> bf16 -> swizzled ds_write
#pragma unroll
    for (int r = 0; r < 4; ++r) {
      int row = arow + r * 32;
      float4 a0 = pa0[r], a1 = pa1[r];
      nacc[r] += a0.x * a0.x + a0.y * a0.y + a0.z * a0.z + a0.w * a0.w
               + a1.x * a1.x + a1.y * a1.y + a1.z * a1.z + a1.w * a1.w;
      u16x8 p = {f2b(a0.x), f2b(a0.y), f2b(a0.z), f2b(a0.w),
                 f2b(a1.x), f2b(a1.y), f2b(a1.z), f2b(a1.w)};
      int gl = (tid & 7) ^ (row & 7);
      *(u16x8*)(lA + (size_t)row * 64 + gl * 8) = p;
    }
    __syncthreads();
    // prefetch A(kt+1); drains under the MFMA phase
    if (kt < 7) {
#pragma unroll
      for (int r = 0; r < 4; ++r) {
        const float* src = Ax + (size_t)(arow + r * 32) * FEAT + (kt + 1) * 64 + acol;
        pa0[r] = *(const float4*)src;
        pa1[r] = *(const float4*)(src + 4);
      }
    }
#pragma unroll
    for (int ks = 0; ks < 2; ++ks) {
      const int gsw = ((ks * 4 + (lane >> 4)) ^ swz) * 8;
      bf16x8 af[4], bb[4];
#pragma unroll
      for (int mi = 0; mi < 4; ++mi)
        af[mi] = *(const bf16x8*)(lA + ((wr * 64 + mi * 16 + lrow) * 64 + gsw));
#pragma unroll
      for (int ni = 0; ni < 4; ++ni)
        bb[ni] = *(const bf16x8*)(lB + ((wc * 64 + ni * 16 + lrow) * 64 + gsw));
#pragma unroll
      for (int mi = 0; mi < 4; ++mi)
#pragma unroll
        for (int ni = 0; ni < 4; ++ni)
          acc[mi][ni] = __builtin_amdgcn_mfma_f32_16x16x32_bf16(af[mi], bb[ni], acc[mi][ni], 0, 0, 0);
    }
    __syncthreads();
  }

  // norm reduce (8 threads share a row) -> cvbuf[local row]
#pragma unroll
  for (int r = 0; r < 4; ++r) {
    float s = nacc[r];
    s += __shfl_xor(s, 1, 64);
    s += __shfl_xor(s, 2, 64);
    s += __shfl_xor(s, 4, 64);
    if ((lane & 7) == 0) cvbuf[arow + r * 32] = -0.5f * s - 3.11916231f;  // -0.5*ln(512)
  }
  __syncthreads();

  // epilogue
  const int cbase = n0 + wc * 64 + lrow;
  const int lrbase = wr * 64 + ((lane >> 4) << 2);
  float colp[4] = {0.f, 0.f, 0.f, 0.f};
  float k1v[4];
  if (!TRANSK) {
#pragma unroll
    for (int ni = 0; ni < 4; ++ni) k1v[ni] = k1[cbase + ni * 16];
  }
#pragma unroll
  for (int mi = 0; mi < 4; ++mi) {
    int lr0 = lrbase + mi * 16;
    float cv[4];
#pragma unroll
    for (int j = 0; j < 4; ++j) cv[j] = cvbuf[lr0 + j];
    if (TRANSK) {
#pragma unroll
      for (int ni = 0; ni < 4; ++ni) {
        int col = cbase + ni * 16;
        u16x4 pk;
#pragma unroll
        for (int j = 0; j < 4; ++j) {
          float e = __expf(acc[mi][ni][j] + cv[j]);
          pk[j] = f2b(e);
          colp[ni] += e;
        }
        *(u16x4*)(Out + (size_t)col * N_NODES + m0 + lr0) = pk;
      }
    } else {
#pragma unroll
      for (int j = 0; j < 4; ++j) {
        float t = 0.f;
#pragma unroll
        for (int ni = 0; ni < 4; ++ni) {
          float e = __expf(acc[mi][ni][j] + cv[j]);
          Out[(size_t)(m0 + lr0 + j) * FEAT + cbase + ni * 16] = f2b(e);
          t += e * k1v[ni];
        }
        t += __shfl_xor(t, 1, 64);
        t += __shfl_xor(t, 2, 64);
        t += __shfl_xor(t, 4, 64);
        t += __shfl_xor(t, 8, 64);
        if (lrow == 0) atomicAdd(&dd[m0 + lr0 + j], t);
      }
    }
  }
  if (TRANSK) {
#pragma unroll
    for (int ni = 0; ni < 4; ++ni) {
      float t = colp[ni];
      t += __shfl_xor(t, 16, 64);
      t += __shfl_xor(t, 32, 64);
      if (lane < 16) atomicAdd(&k1w[n0 + wc * 64 + lane + ni * 16], t);
    }
  }
}

// ---- kv split-K GEMM: partials[z][feat][d] ----
__global__ __launch_bounds__(256) void k_kv(const ushort_t* __restrict__ KT,
                                            const ushort_t* __restrict__ VT,
                                            float* __restrict__ P) {
  __shared__ ushort_t lA[128 * 64], lB[128 * 64];
  f32x4 acc[4][4];
#pragma unroll
  for (int i = 0; i < 4; ++i)
#pragma unroll
    for (int j = 0; j < 4; ++j) acc[i][j] = (f32x4){0.f, 0.f, 0.f, 0.f};
  const int m0 = blockIdx.y * 128, n0 = blockIdx.x * 128, z = blockIdx.z;
  gemm_tile(KT + (size_t)m0 * N_NODES + z * 2048,
            VT + (size_t)n0 * N_NODES + z * 2048, N_NODES, N_NODES, 32, lA, lB, acc);
  float* Pz = P + (size_t)z * (FEAT * FEAT);
  const int lane = threadIdx.x & 63, wid = threadIdx.x >> 6;
  const int wr = wid >> 1, wc = wid & 1;
  const int cbase = n0 + wc * 64 + (lane & 15);
  const int rbase = m0 + wr * 64 + ((lane >> 4) << 2);
#pragma unroll
  for (int mi = 0; mi < 4; ++mi)
#pragma unroll
    for (int ni = 0; ni < 4; ++ni)
#pragma unroll
      for (int j = 0; j < 4; ++j)
        Pz[(size_t)(rbase + mi * 16 + j) * FEAT + cbase + ni * 16] = acc[mi][ni][j];
}

// ---- reduce partials -> kvT bf16 [d][feat] ----
__global__ __launch_bounds__(256) void k_redkv(const float* __restrict__ P,
                                               ushort_t* __restrict__ kvT) {
  int t = blockIdx.x * 256 + threadIdx.x;  // 0..65535
  int m = t >> 7;       // feat 0..511
  int d4 = t & 127;     // d/4
  float4 s = {0.f, 0.f, 0.f, 0.f};
  for (int z = 0; z < 32; ++z) {
    float4 v = *(const float4*)(P + (size_t)z * (FEAT * FEAT) + (size_t)m * FEAT + d4 * 4);
    s.x += v.x; s.y += v.y; s.z += v.z; s.w += v.w;
  }
  kvT[(size_t)(d4 * 4 + 0) * FEAT + m] = f2b(s.x);
  kvT[(size_t)(d4 * 4 + 1) * FEAT + m] = f2b(s.y);
  kvT[(size_t)(d4 * 4 + 2) * FEAT + m] = f2b(s.z);
  kvT[(size_t)(d4 * 4 + 3) * FEAT + m] = f2b(s.w);
}

// ---- final GEMM: out = (Q_hat @ kv) / dd ----
__global__ __launch_bounds__(256) void k_final(const ushort_t* __restrict__ Qh,
                                               const ushort_t* __restrict__ kvT,
                                               const float* __restrict__ dd,
                                               float* __restrict__ out) {
  __shared__ ushort_t lA[128 * 64], lB[128 * 64];
  f32x4 acc[4][4];
#pragma unroll
  for (int i = 0; i < 4; ++i)
#pragma unroll
    for (int j = 0; j < 4; ++j) acc[i][j] = (f32x4){0.f, 0.f, 0.f, 0.f};
  const int m0 = blockIdx.y * 128, n0 = blockIdx.x * 128;
  gemm_tile(Qh + (size_t)m0 * FEAT, kvT + (size_t)n0 * FEAT, FEAT, FEAT, 8, lA, lB, acc);
  const int lane = threadIdx.x & 63, wid = threadIdx.x >> 6;
  const int wr = wid >> 1, wc = wid & 1;
  const int cbase = n0 + wc * 64 + (lane & 15);
  const int rbase = m0 + wr * 64 + ((lane >> 4) << 2);
#pragma unroll
  for (int mi = 0; mi < 4; ++mi) {
    int r0 = rbase + mi * 16;
    float inv[4];
#pragma unroll
    for (int j = 0; j < 4; ++j) inv[j] = 1.0f / dd[r0 + j];
#pragma unroll
    for (int ni = 0; ni < 4; ++ni) {
      int col = cbase + ni * 16;
#pragma unroll
      for (int j = 0; j < 4; ++j)
        out[(size_t)(r0 + j) * FEAT + col] = acc[mi][ni][j] * inv[j];
    }
  }
}

extern "C" void kernel_launch(void* const* d_in, const int* in_sizes, int n_in,
                              void* d_out, int out_size, void* d_ws, size_t ws_size,
                              hipStream_t stream) {
  const float* Q = (const float*)d_in[0];
  const float* K = (const float*)d_in[1];
  const float* V = (const float*)d_in[2];
  const float* omega = (const float*)d_in[3];
  float* out = (float*)d_out;

  char* ws = (char*)d_ws;
  ushort_t* B1  = (ushort_t*)(ws);                  // 64 MB: V^T
  ushort_t* B2  = (ushort_t*)(ws + 67108864);       // 64 MB: K_hat^T -> Q_hat
  ushort_t* Ob  = (ushort_t*)(ws + 134217728);      // 512 KB omega bf16
  ushort_t* kvT = (ushort_t*)(ws + 134742016);      // 512 KB kv^T bf16
  float*    k1  = (float*)(ws + 135266304);         // 2 KB k_ones
  float*    dd  = (float*)(ws + 135268352);         // 256 KB d_diag (contiguous after k1)
  // split-K partials (32 MB) aliased into d_out: fully consumed by k_redkv
  // before k_final overwrites d_out (stream-ordered).
  float*    P   = (float*)d_out;

  k_init<<<256 + 258, 256, 0, stream>>>(omega, Ob, k1, 512 + 65536);
  k_phi_fused<1><<<dim3(4, 512), 256, 0, stream>>>(K, Ob, k1, k1, dd, B2);  // -> K_hat^T, k1
  k_vt<<<dim3(N_NODES / 64, 8), 256, 0, stream>>>(V, B1);                   // -> V^T
  k_kv<<<dim3(4, 4, 32), 256, 0, stream>>>(B2, B1, P);
  k_phi_fused<0><<<dim3(4, 512), 256, 0, stream>>>(Q, Ob, k1, k1, dd, B2);  // -> Q_hat, dd
  k_redkv<<<256, 256, 0, stream>>>(P, kvT);
  k_final<<<dim3(4, 512), 256, 0, stream>>>(B2, kvT, dd, out);
}